// Round 17
// baseline (118.131 us; speedup 1.0000x reference)
//
#include <hip/hip_runtime.h>
#include <cstdint>

#define CIN 96
#define DIN 96
#define DTR 8
#define DST 16
#define HH 128
#define WW 128
#define HW (HH*WW)
#define NPIX (2*HW)       // B=2
#define DIAG (WW+1)       // global diagonal step = 129
#define LOG2E 1.4426950408889634f
#define NREP 3            // diagnostic repeats (idempotent / dummy-redirected)

__device__ __forceinline__ float softplus_f(float t) {
    return (t > 20.0f) ? t : __logf(1.0f + __expf(t));
}

__device__ __forceinline__ void load_An(const float* __restrict__ AwsT, int d, float* An) {
    float4 A0 = *reinterpret_cast<const float4*>(AwsT + d * 16);
    float4 A1 = *reinterpret_cast<const float4*>(AwsT + d * 16 + 4);
    float4 A2 = *reinterpret_cast<const float4*>(AwsT + d * 16 + 8);
    float4 A3 = *reinterpret_cast<const float4*>(AwsT + d * 16 + 12);
    An[0]=A0.x; An[1]=A0.y; An[2]=A0.z; An[3]=A0.w;
    An[4]=A1.x; An[5]=A1.y; An[6]=A1.z; An[7]=A1.w;
    An[8]=A2.x; An[9]=A2.y; An[10]=A2.z; An[11]=A2.w;
    An[12]=A3.x; An[13]=A3.y; An[14]=A3.z; An[15]=A3.w;
}

__device__ __forceinline__ float c_dot(const float* __restrict__ rc, const float* acc16) {
    float4 C0 = *reinterpret_cast<const float4*>(rc);
    float4 C1 = *reinterpret_cast<const float4*>(rc + 4);
    float4 C2 = *reinterpret_cast<const float4*>(rc + 8);
    float4 C3 = *reinterpret_cast<const float4*>(rc + 12);
    float ys = 0.f;
    ys = fmaf(acc16[0],C0.x,ys); ys = fmaf(acc16[1],C0.y,ys);
    ys = fmaf(acc16[2],C0.z,ys); ys = fmaf(acc16[3],C0.w,ys);
    ys = fmaf(acc16[4],C1.x,ys); ys = fmaf(acc16[5],C1.y,ys);
    ys = fmaf(acc16[6],C1.z,ys); ys = fmaf(acc16[7],C1.w,ys);
    ys = fmaf(acc16[8],C2.x,ys); ys = fmaf(acc16[9],C2.y,ys);
    ys = fmaf(acc16[10],C2.z,ys); ys = fmaf(acc16[11],C2.w,ys);
    ys = fmaf(acc16[12],C3.x,ys); ys = fmaf(acc16[13],C3.y,ys);
    ys = fmaf(acc16[14],C3.z,ys); ys = fmaf(acc16[15],C3.w,ys);
    return ys;
}

// ---------------- Kernel 1: 2x32 tile (r13 structure), body repeated NREP (idempotent) ----------------
__global__ __launch_bounds__(512) void ssm2d_dbc(
    const float* __restrict__ x,
    const float* __restrict__ W1, const float* __restrict__ b1,
    const float* __restrict__ dtw, const float* __restrict__ dtb,
    const float* __restrict__ alog, const float* __restrict__ Dv,
    float* __restrict__ bc, float2* __restrict__ dc,
    float* __restrict__ Aws, float* __restrict__ out)
{
    __shared__ float sX[CIN][65];
    __shared__ float sOut[64][41];
    __shared__ float sDelta[DIN][65];
    __shared__ float sAn[DIN][17];
    __shared__ float sBC[64];

    const int t = threadIdx.x;
    const int blk = blockIdx.x;
    const int b = blk >> 8;
    const int tile = blk & 255;
    const int a = tile >> 2;
    const int b2 = tile & 3;
    const int r0 = a << 1;
    const int c0 = b2 << 5;
    const float* xb = x + (size_t)b * CIN * HW;

    for (int rep = 0; rep < NREP; ++rep) {
        #pragma unroll
        for (int it = 0; it < 3; ++it) {
            int i4 = it * 512 + t;
            int ch = i4 >> 4;
            int px4 = (i4 & 15) << 2;
            int row = r0 + (px4 >> 5);
            int col = c0 + (px4 & 31);
            float4 v = *reinterpret_cast<const float4*>(xb + (size_t)ch * HW + row * WW + col);
            sX[ch][px4 + 0] = v.x; sX[ch][px4 + 1] = v.y;
            sX[ch][px4 + 2] = v.z; sX[ch][px4 + 3] = v.w;
        }
        for (int i = t; i < DIN * DST; i += 512) {
            float v = -__expf(alog[i]) * LOG2E;
            sAn[i >> 4][i & 15] = v;
            if (blk == 0) Aws[i] = v;
        }
        __syncthreads();

        const int lane = t & 63;
        const int w = __builtin_amdgcn_readfirstlane(t >> 6);
        const int og = w * 5;
        float a0 = b1[og + 0], a1 = b1[og + 1], a2 = b1[og + 2],
              a3 = b1[og + 3], a4 = b1[og + 4];
        #pragma unroll 16
        for (int ch = 0; ch < CIN; ++ch) {
            float xv = sX[ch][lane];
            a0 = fmaf(xv, W1[(og + 0) * CIN + ch], a0);
            a1 = fmaf(xv, W1[(og + 1) * CIN + ch], a1);
            a2 = fmaf(xv, W1[(og + 2) * CIN + ch], a2);
            a3 = fmaf(xv, W1[(og + 3) * CIN + ch], a3);
            a4 = fmaf(xv, W1[(og + 4) * CIN + ch], a4);
        }
        sOut[lane][og + 0] = a0; sOut[lane][og + 1] = a1; sOut[lane][og + 2] = a2;
        sOut[lane][og + 3] = a3; sOut[lane][og + 4] = a4;
        __syncthreads();

        if (t < 64) {
            float s = 0.f;
            #pragma unroll
            for (int n = 0; n < DST; ++n) s += sOut[t][8 + n] * sOut[t][24 + n];
            sBC[t] = s;
        }
        __syncthreads();

        #pragma unroll
        for (int it = 0; it < 12; ++it) {
            int i = it * 512 + t;
            int px = i / 96;
            int d = i - px * 96;
            float tt = dtb[d];
            float4 wA = *reinterpret_cast<const float4*>(dtw + d * DTR);
            float4 wB = *reinterpret_cast<const float4*>(dtw + d * DTR + 4);
            tt = fmaf(sOut[px][0], wA.x, tt); tt = fmaf(sOut[px][1], wA.y, tt);
            tt = fmaf(sOut[px][2], wA.z, tt); tt = fmaf(sOut[px][3], wA.w, tt);
            tt = fmaf(sOut[px][4], wB.x, tt); tt = fmaf(sOut[px][5], wB.y, tt);
            tt = fmaf(sOut[px][6], wB.z, tt); tt = fmaf(sOut[px][7], wB.w, tt);
            float delta = softplus_f(tt);
            float xv = sX[d][px];
            sDelta[d][px] = delta;
            int rg = r0 + (px >> 5), cg = c0 + (px & 31);
            size_t pg = (size_t)b * HW + rg * WW + cg;
            out[pg * 96 + d] = xv * fmaf(delta, sBC[px], Dv[d]);
            if (((rg - cg) & 3) == 0)
                dc[pg * 96 + d] = make_float2(delta, delta * xv);
        }
        #pragma unroll
        for (int it = 0; it < 4; ++it) {
            int i = it * 512 + t;
            int px = i >> 5;
            int n = i & 31;
            int rg = r0 + (px >> 5), cg = c0 + (px & 31);
            if (((rg - cg) & 3) == 0) {
                size_t pg = (size_t)b * HW + rg * WW + cg;
                bc[pg * 32 + n] = sOut[px][8 + n];
            }
        }
        __syncthreads();

        for (int ii = t; ii < 16 * 96; ii += 512) {
            int k = ii / 96;
            int d = ii - k * 96;
            bool live = !((a & 1) && (k & 1));
            int pxd = 33 + 2 * k;
            int anc = 2 * k;
            float ddst = sDelta[d][pxd];
            float ca = sDelta[d][anc] * sX[d][anc];
            float y = 0.f;
            #pragma unroll
            for (int n = 0; n < 16; ++n)
                y = fmaf(sOut[pxd][24 + n] * exp2f(sAn[d][n] * ddst) * sOut[anc][8 + n], ca, y);
            if (live) {
                int rg = r0 + 1, cg = c0 + 1 + 2 * k;
                size_t g = ((size_t)b * HW + rg * WW + cg) * 96 + d;
                out[g] += y;
            }
        }
        __syncthreads();
    }
}

template<int M>
__device__ __forceinline__ void decode_item(int e, int& p, int& d, bool& live) {
    d = e % 96;
    int pxi = e / 96;
    const int sh = 7 - M;
    const int nM = 1 << sh;
    const int half = nM * nM;
    int img = pxi >= half;
    int e2 = pxi - (img ? half : 0);
    int rr = e2 >> sh;
    int cc = e2 & (nM - 1);
    live = ((rr & cc & 1) == 0);
    int r = ((rr + 1) << M) - 1;
    int c = ((cc + 1) << M) - 1;
    p = img * HW + r * WW + c;
}

template<int L>
__device__ __forceinline__ void chain_LT(int p, int d, bool live,
    const float* __restrict__ bc, const float2* __restrict__ dc,
    const float* __restrict__ AwsT, float* __restrict__ out)
{
    size_t base = (size_t)p * 96 + d;
    float2 v0 = dc[base];
    float2 vj[L - 1];
    #pragma unroll
    for (int j = 1; j < L; ++j)
        vj[j - 1] = dc[(size_t)(p - j * DIAG) * 96 + d];
    float An[16];
    load_An(AwsT, d, An);
    float acc16[16];
    #pragma unroll
    for (int n = 0; n < 16; ++n) acc16[n] = 0.f;
    float S = v0.x;
    #pragma unroll
    for (int j = 1; j < L; ++j) {
        const float* rb = bc + (size_t)(p - j * DIAG) * 32;
        float4 B0 = *reinterpret_cast<const float4*>(rb);
        float4 B1 = *reinterpret_cast<const float4*>(rb + 4);
        float4 B2 = *reinterpret_cast<const float4*>(rb + 8);
        float4 B3 = *reinterpret_cast<const float4*>(rb + 12);
        float Bv[16] = {B0.x,B0.y,B0.z,B0.w, B1.x,B1.y,B1.z,B1.w,
                        B2.x,B2.y,B2.z,B2.w, B3.x,B3.y,B3.z,B3.w};
        float cj = vj[j - 1].y;
        #pragma unroll
        for (int n = 0; n < 16; ++n)
            acc16[n] = fmaf(exp2f(An[n] * S) * Bv[n], cj, acc16[n]);
        S += vj[j - 1].x;
    }
    float ys = c_dot(bc + (size_t)p * 32 + 16, acc16);
    if (live) out[base] += ys;
}

__device__ __forceinline__ void chain_RT(int p, int d, int L, bool live,
    const float* __restrict__ bc, const float2* __restrict__ dc,
    const float* __restrict__ AwsT, float* __restrict__ out)
{
    size_t base = (size_t)p * 96 + d;
    float An[16];
    load_An(AwsT, d, An);
    float acc16[16];
    #pragma unroll
    for (int n = 0; n < 16; ++n) acc16[n] = 0.f;
    float S = dc[base].x;
    int pj = p;
    for (int j = 1; j < L; ++j) {
        pj -= DIAG;
        float2 v = dc[(size_t)pj * 96 + d];
        const float* rb = bc + (size_t)pj * 32;
        float4 B0 = *reinterpret_cast<const float4*>(rb);
        float4 B1 = *reinterpret_cast<const float4*>(rb + 4);
        float4 B2 = *reinterpret_cast<const float4*>(rb + 8);
        float4 B3 = *reinterpret_cast<const float4*>(rb + 12);
        float Bv[16] = {B0.x,B0.y,B0.z,B0.w, B1.x,B1.y,B1.z,B1.w,
                        B2.x,B2.y,B2.z,B2.w, B3.x,B3.y,B3.z,B3.w};
        #pragma unroll
        for (int n = 0; n < 16; ++n)
            acc16[n] = fmaf(exp2f(An[n] * S) * Bv[n], v.y, acc16[n]);
        S += v.x;
    }
    float ys = c_dot(bc + (size_t)p * 32 + 16, acc16);
    if (live) out[base] += ys;
}

// ---------------- Kernel 2: body repeated NREP; reps 0..NREP-2 write dummy ----------------
#define K2_M2 768
#define K2_M3 192
#define K2_M4 48
#define K2_LONG 768
__global__ __launch_bounds__(256) void ssm2d_scan(
    const float* __restrict__ bc, const float2* __restrict__ dc,
    const float* __restrict__ AwsT, float* __restrict__ out,
    float* __restrict__ dummy)
{
    const int t = threadIdx.x;
    const int blk = blockIdx.x;

    for (int rep = 0; rep < NREP; ++rep) {
        float* oo = (rep == NREP - 1) ? out : dummy;

        if (blk < K2_M2) {
            int e = blk * 256 + t;
            int p, d; bool live;
            decode_item<2>(e, p, d, live);
            chain_LT<4>(p, d, live, bc, dc, AwsT, oo);
        } else if (blk < K2_M2 + K2_M3) {
            int e = (blk - K2_M2) * 256 + t;
            int p, d; bool live;
            decode_item<3>(e, p, d, live);
            chain_RT(p, d, 8, live, bc, dc, AwsT, oo);
        } else if (blk < K2_M2 + K2_M3 + K2_M4) {
            int e = (blk - K2_M2 - K2_M3) * 256 + t;
            int p, d; bool live;
            decode_item<4>(e, p, d, live);
            chain_RT(p, d, 16, live, bc, dc, AwsT, oo);
        } else {
            const int wv = t >> 6;
            const int lane = t & 63;
            int waveid = (blk - (K2_M2 + K2_M3 + K2_M4)) * 4 + wv;
            int pix = waveid / DIN;
            int d = waveid - pix * DIN;
            int batch = pix >> 4;
            int sel = pix & 15;
            int r = ((sel >> 2) + 1) * 32 - 1;
            int c = ((sel & 3) + 1) * 32 - 1;
            int p = batch * HW + r * WW + c;
            int m = __builtin_ctz(r + 1);
            int mc = __builtin_ctz(c + 1);
            if (mc < m) m = mc;
            int L = 1 << m;

            float An[16];
            load_An(AwsT, d, An);
            float acc16[16];
            #pragma unroll
            for (int n = 0; n < 16; ++n) acc16[n] = 0.0f;
            float Scarry = 0.0f;

            for (int jb = 0; jb < L; jb += 64) {
                int j = jb + lane;
                bool act = (j < L);
                int jc = act ? j : 0;
                int pj = p - DIAG * jc;
                float2 v = dc[(size_t)pj * 96 + d];
                float dj = act ? v.x : 0.0f;
                float cj = (j >= 1 && act) ? v.y : 0.0f;

                float incl = dj;
                #pragma unroll
                for (int off = 1; off < 64; off <<= 1) {
                    float u = __shfl_up(incl, off);
                    if (lane >= off) incl += u;
                }
                float S = Scarry + incl - dj;

                const float* rb = bc + (size_t)pj * 32;
                float4 B0 = *reinterpret_cast<const float4*>(rb);
                float4 B1 = *reinterpret_cast<const float4*>(rb + 4);
                float4 B2 = *reinterpret_cast<const float4*>(rb + 8);
                float4 B3 = *reinterpret_cast<const float4*>(rb + 12);
                float Bv[16] = {B0.x,B0.y,B0.z,B0.w, B1.x,B1.y,B1.z,B1.w,
                                B2.x,B2.y,B2.z,B2.w, B3.x,B3.y,B3.z,B3.w};
                #pragma unroll
                for (int n = 0; n < 16; ++n)
                    acc16[n] = fmaf(exp2f(An[n] * S) * Bv[n], cj, acc16[n]);

                Scarry += __shfl(incl, 63);
            }

            #pragma unroll
            for (int off = 32; off >= 1; off >>= 1) {
                #pragma unroll
                for (int n = 0; n < 16; ++n) acc16[n] += __shfl_xor(acc16[n], off);
            }

            if (lane == 0) {
                float y = c_dot(bc + (size_t)p * 32 + 16, acc16);
                oo[(size_t)p * 96 + d] += y;
            }
        }
    }
}

extern "C" void kernel_launch(void* const* d_in, const int* in_sizes, int n_in,
                              void* d_out, int out_size, void* d_ws, size_t ws_size,
                              hipStream_t stream) {
    const float* x    = (const float*)d_in[0];
    const float* W1   = (const float*)d_in[1];
    const float* b1   = (const float*)d_in[2];
    const float* dtw  = (const float*)d_in[3];
    const float* dtb  = (const float*)d_in[4];
    const float* alog = (const float*)d_in[5];
    const float* Dv   = (const float*)d_in[6];
    float* out = (float*)d_out;

    char* ws = (char*)d_ws;
    float2* dc    = (float2*)(ws);               // NPIX*96*8 (quarter-touched)
    float*  bcb   = (float*)(ws + 25165824);     // NPIX*32*4 (quarter-touched)
    float*  Aws   = (float*)(ws + 29360128);     // 1536*4
    float*  dummy = (float*)(ws + 33554432);     // 12.6 MB scratch for diagnostic reps

    hipLaunchKernelGGL(ssm2d_dbc, dim3(512), dim3(512), 0, stream,
                       x, W1, b1, dtw, dtb, alog, Dv,
                       bcb, dc, Aws, out);
    hipLaunchKernelGGL(ssm2d_scan, dim3(K2_M2 + K2_M3 + K2_M4 + K2_LONG), dim3(256), 0, stream,
                       bcb, dc, Aws, out, dummy);
}

// Round 18
// 41.297 us; speedup vs baseline: 2.8605x; 2.8605x over previous
//
#include <hip/hip_runtime.h>
#include <cstdint>

#define CIN 96
#define DIN 96
#define DTR 8
#define DST 16
#define HH 128
#define WW 128
#define HW (HH*WW)
#define NPIX (2*HW)       // B=2
#define DIAG (WW+1)       // global diagonal step = 129
#define LOG2E 1.4426950408889634f

__device__ __forceinline__ float softplus_f(float t) {
    return (t > 20.0f) ? t : __logf(1.0f + __expf(t));
}

__device__ __forceinline__ void load_An(const float* __restrict__ AwsT, int d, float* An) {
    float4 A0 = *reinterpret_cast<const float4*>(AwsT + d * 16);
    float4 A1 = *reinterpret_cast<const float4*>(AwsT + d * 16 + 4);
    float4 A2 = *reinterpret_cast<const float4*>(AwsT + d * 16 + 8);
    float4 A3 = *reinterpret_cast<const float4*>(AwsT + d * 16 + 12);
    An[0]=A0.x; An[1]=A0.y; An[2]=A0.z; An[3]=A0.w;
    An[4]=A1.x; An[5]=A1.y; An[6]=A1.z; An[7]=A1.w;
    An[8]=A2.x; An[9]=A2.y; An[10]=A2.z; An[11]=A2.w;
    An[12]=A3.x; An[13]=A3.y; An[14]=A3.z; An[15]=A3.w;
}

__device__ __forceinline__ float c_dot(const float* __restrict__ rc, const float* acc16) {
    float4 C0 = *reinterpret_cast<const float4*>(rc);
    float4 C1 = *reinterpret_cast<const float4*>(rc + 4);
    float4 C2 = *reinterpret_cast<const float4*>(rc + 8);
    float4 C3 = *reinterpret_cast<const float4*>(rc + 12);
    float ys = 0.f;
    ys = fmaf(acc16[0],C0.x,ys); ys = fmaf(acc16[1],C0.y,ys);
    ys = fmaf(acc16[2],C0.z,ys); ys = fmaf(acc16[3],C0.w,ys);
    ys = fmaf(acc16[4],C1.x,ys); ys = fmaf(acc16[5],C1.y,ys);
    ys = fmaf(acc16[6],C1.z,ys); ys = fmaf(acc16[7],C1.w,ys);
    ys = fmaf(acc16[8],C2.x,ys); ys = fmaf(acc16[9],C2.y,ys);
    ys = fmaf(acc16[10],C2.z,ys); ys = fmaf(acc16[11],C2.w,ys);
    ys = fmaf(acc16[12],C3.x,ys); ys = fmaf(acc16[13],C3.y,ys);
    ys = fmaf(acc16[14],C3.z,ys); ys = fmaf(acc16[15],C3.w,ys);
    return ys;
}

// ---------------- Kernel 1: 2x32 tile: GEMV + delta + base out + in-LDS L=2 chains ----------------
// r13 structure, minus sDelta (chain recomputes deltas from sOut); 3 blocks/CU target.
__global__ __launch_bounds__(512, 6) void ssm2d_dbc(
    const float* __restrict__ x,
    const float* __restrict__ W1, const float* __restrict__ b1,
    const float* __restrict__ dtw, const float* __restrict__ dtb,
    const float* __restrict__ alog, const float* __restrict__ Dv,
    float* __restrict__ bc, float2* __restrict__ dc,
    float* __restrict__ Aws, float* __restrict__ out)
{
    __shared__ float sX[CIN][65];      // 24.96 KB
    __shared__ float sOut[64][41];     // 10.5 KB
    __shared__ float sAn[DIN][17];     // 6.53 KB
    __shared__ float sBC[64];          // 0.25 KB   -> total ~42.3 KB

    const int t = threadIdx.x;
    const int blk = blockIdx.x;          // 0..511
    const int b = blk >> 8;
    const int tile = blk & 255;
    const int a = tile >> 2;             // row-pair 0..63
    const int b2 = tile & 3;             // col-tile 0..3
    const int r0 = a << 1;
    const int c0 = b2 << 5;
    const float* xb = x + (size_t)b * CIN * HW;

    // load x tile (96 ch x 64 px) as float4
    #pragma unroll
    for (int it = 0; it < 3; ++it) {
        int i4 = it * 512 + t;           // < 1536
        int ch = i4 >> 4;
        int px4 = (i4 & 15) << 2;
        int row = r0 + (px4 >> 5);
        int col = c0 + (px4 & 31);
        float4 v = *reinterpret_cast<const float4*>(xb + (size_t)ch * HW + row * WW + col);
        sX[ch][px4 + 0] = v.x; sX[ch][px4 + 1] = v.y;
        sX[ch][px4 + 2] = v.z; sX[ch][px4 + 3] = v.w;
    }
    // A table (LDS; block 0 publishes global copy for kernel 2)
    for (int i = t; i < DIN * DST; i += 512) {
        float v = -__expf(alog[i]) * LOG2E;
        sAn[i >> 4][i & 15] = v;
        if (blk == 0) Aws[i] = v;
    }
    __syncthreads();

    // GEMV: wave w computes outputs [5w,5w+5), lane = pixel
    const int lane = t & 63;
    const int w = __builtin_amdgcn_readfirstlane(t >> 6);   // 0..7
    const int og = w * 5;
    float a0 = b1[og + 0], a1 = b1[og + 1], a2 = b1[og + 2],
          a3 = b1[og + 3], a4 = b1[og + 4];
    #pragma unroll 16
    for (int ch = 0; ch < CIN; ++ch) {
        float xv = sX[ch][lane];
        a0 = fmaf(xv, W1[(og + 0) * CIN + ch], a0);
        a1 = fmaf(xv, W1[(og + 1) * CIN + ch], a1);
        a2 = fmaf(xv, W1[(og + 2) * CIN + ch], a2);
        a3 = fmaf(xv, W1[(og + 3) * CIN + ch], a3);
        a4 = fmaf(xv, W1[(og + 4) * CIN + ch], a4);
    }
    sOut[lane][og + 0] = a0; sOut[lane][og + 1] = a1; sOut[lane][og + 2] = a2;
    sOut[lane][og + 3] = a3; sOut[lane][og + 4] = a4;
    __syncthreads();

    if (t < 64) {
        float s = 0.f;
        #pragma unroll
        for (int n = 0; n < DST; ++n) s += sOut[t][8 + n] * sOut[t][24 + n];
        sBC[t] = s;
    }
    __syncthreads();

    // epilogue: delta + base out; sparse dc ((r-c) % 4 == 0)
    #pragma unroll
    for (int it = 0; it < 12; ++it) {
        int i = it * 512 + t;            // < 6144
        int px = i / 96;
        int d = i - px * 96;
        float tt = dtb[d];
        float4 wA = *reinterpret_cast<const float4*>(dtw + d * DTR);
        float4 wB = *reinterpret_cast<const float4*>(dtw + d * DTR + 4);
        tt = fmaf(sOut[px][0], wA.x, tt); tt = fmaf(sOut[px][1], wA.y, tt);
        tt = fmaf(sOut[px][2], wA.z, tt); tt = fmaf(sOut[px][3], wA.w, tt);
        tt = fmaf(sOut[px][4], wB.x, tt); tt = fmaf(sOut[px][5], wB.y, tt);
        tt = fmaf(sOut[px][6], wB.z, tt); tt = fmaf(sOut[px][7], wB.w, tt);
        float delta = softplus_f(tt);
        float xv = sX[d][px];
        int rg = r0 + (px >> 5), cg = c0 + (px & 31);
        size_t pg = (size_t)b * HW + rg * WW + cg;
        out[pg * 96 + d] = xv * fmaf(delta, sBC[px], Dv[d]);
        if (((rg - cg) & 3) == 0)
            dc[pg * 96 + d] = make_float2(delta, delta * xv);
    }
    // sparse bc writeout ((r-c) % 4 == 0 pixels)
    #pragma unroll
    for (int it = 0; it < 4; ++it) {
        int i = it * 512 + t;            // < 2048
        int px = i >> 5;
        int n = i & 31;
        int rg = r0 + (px >> 5), cg = c0 + (px & 31);
        if (((rg - cg) & 3) == 0) {
            size_t pg = (size_t)b * HW + rg * WW + cg;
            bc[pg * 32 + n] = sOut[px][8 + n];
        }
    }
    __syncthreads();   // base out drained before chain RMW

    // in-LDS M1 chains (L=2): dst (2a+1, c0+1+2k), anc (2a, c0+2k); deltas recomputed from sOut
    for (int ii = t; ii < 16 * 96; ii += 512) {
        int k = ii / 96;                 // 0..15
        int d = ii - k * 96;
        bool live = !((a & 1) && (k & 1));   // exact m==1
        int pxd = 33 + 2 * k;
        int anc = 2 * k;
        float4 wA = *reinterpret_cast<const float4*>(dtw + d * DTR);
        float4 wB = *reinterpret_cast<const float4*>(dtw + d * DTR + 4);
        float tb = dtb[d];
        float t1 = tb, t2 = tb;
        t1 = fmaf(sOut[pxd][0], wA.x, t1); t1 = fmaf(sOut[pxd][1], wA.y, t1);
        t1 = fmaf(sOut[pxd][2], wA.z, t1); t1 = fmaf(sOut[pxd][3], wA.w, t1);
        t1 = fmaf(sOut[pxd][4], wB.x, t1); t1 = fmaf(sOut[pxd][5], wB.y, t1);
        t1 = fmaf(sOut[pxd][6], wB.z, t1); t1 = fmaf(sOut[pxd][7], wB.w, t1);
        t2 = fmaf(sOut[anc][0], wA.x, t2); t2 = fmaf(sOut[anc][1], wA.y, t2);
        t2 = fmaf(sOut[anc][2], wA.z, t2); t2 = fmaf(sOut[anc][3], wA.w, t2);
        t2 = fmaf(sOut[anc][4], wB.x, t2); t2 = fmaf(sOut[anc][5], wB.y, t2);
        t2 = fmaf(sOut[anc][6], wB.z, t2); t2 = fmaf(sOut[anc][7], wB.w, t2);
        float ddst = softplus_f(t1);
        float ca = softplus_f(t2) * sX[d][anc];
        float y = 0.f;
        #pragma unroll
        for (int n = 0; n < 16; ++n)
            y = fmaf(sOut[pxd][24 + n] * exp2f(sAn[d][n] * ddst) * sOut[anc][8 + n], ca, y);
        if (live) {
            int rg = r0 + 1, cg = c0 + 1 + 2 * k;
            size_t g = ((size_t)b * HW + rg * WW + cg) * 96 + d;
            out[g] += y;
        }
    }
}

// decode item for section M (exact-m check) -> (p, d, live)
template<int M>
__device__ __forceinline__ void decode_item(int e, int& p, int& d, bool& live) {
    d = e % 96;
    int pxi = e / 96;
    const int sh = 7 - M;
    const int nM = 1 << sh;
    const int half = nM * nM;
    int img = pxi >= half;
    int e2 = pxi - (img ? half : 0);
    int rr = e2 >> sh;
    int cc = e2 & (nM - 1);
    live = ((rr & cc & 1) == 0);
    int r = ((rr + 1) << M) - 1;
    int c = ((cc + 1) << M) - 1;
    p = img * HW + r * WW + c;
}

template<int L>
__device__ __forceinline__ void chain_LT(int p, int d, bool live,
    const float* __restrict__ bc, const float2* __restrict__ dc,
    const float* __restrict__ AwsT, float* __restrict__ out)
{
    size_t base = (size_t)p * 96 + d;
    float2 v0 = dc[base];
    float2 vj[L - 1];
    #pragma unroll
    for (int j = 1; j < L; ++j)
        vj[j - 1] = dc[(size_t)(p - j * DIAG) * 96 + d];
    float An[16];
    load_An(AwsT, d, An);
    float acc16[16];
    #pragma unroll
    for (int n = 0; n < 16; ++n) acc16[n] = 0.f;
    float S = v0.x;
    #pragma unroll
    for (int j = 1; j < L; ++j) {
        const float* rb = bc + (size_t)(p - j * DIAG) * 32;
        float4 B0 = *reinterpret_cast<const float4*>(rb);
        float4 B1 = *reinterpret_cast<const float4*>(rb + 4);
        float4 B2 = *reinterpret_cast<const float4*>(rb + 8);
        float4 B3 = *reinterpret_cast<const float4*>(rb + 12);
        float Bv[16] = {B0.x,B0.y,B0.z,B0.w, B1.x,B1.y,B1.z,B1.w,
                        B2.x,B2.y,B2.z,B2.w, B3.x,B3.y,B3.z,B3.w};
        float cj = vj[j - 1].y;
        #pragma unroll
        for (int n = 0; n < 16; ++n)
            acc16[n] = fmaf(exp2f(An[n] * S) * Bv[n], cj, acc16[n]);
        S += vj[j - 1].x;
    }
    float ys = c_dot(bc + (size_t)p * 32 + 16, acc16);
    if (live) out[base] += ys;
}

__device__ __forceinline__ void chain_RT(int p, int d, int L, bool live,
    const float* __restrict__ bc, const float2* __restrict__ dc,
    const float* __restrict__ AwsT, float* __restrict__ out)
{
    size_t base = (size_t)p * 96 + d;
    float An[16];
    load_An(AwsT, d, An);
    float acc16[16];
    #pragma unroll
    for (int n = 0; n < 16; ++n) acc16[n] = 0.f;
    float S = dc[base].x;
    int pj = p;
    for (int j = 1; j < L; ++j) {
        pj -= DIAG;
        float2 v = dc[(size_t)pj * 96 + d];
        const float* rb = bc + (size_t)pj * 32;
        float4 B0 = *reinterpret_cast<const float4*>(rb);
        float4 B1 = *reinterpret_cast<const float4*>(rb + 4);
        float4 B2 = *reinterpret_cast<const float4*>(rb + 8);
        float4 B3 = *reinterpret_cast<const float4*>(rb + 12);
        float Bv[16] = {B0.x,B0.y,B0.z,B0.w, B1.x,B1.y,B1.z,B1.w,
                        B2.x,B2.y,B2.z,B2.w, B3.x,B3.y,B3.z,B3.w};
        #pragma unroll
        for (int n = 0; n < 16; ++n)
            acc16[n] = fmaf(exp2f(An[n] * S) * Bv[n], v.y, acc16[n]);
        S += v.x;
    }
    float ys = c_dot(bc + (size_t)p * 32 + 16, acc16);
    if (live) out[base] += ys;
}

// ---------------- Kernel 2: M2 (L=4), M3 (L=8), M4 (L=16), long (m>=5) ----------------
#define K2_M2 768
#define K2_M3 192
#define K2_M4 48
#define K2_LONG 768
__global__ __launch_bounds__(256) void ssm2d_scan(
    const float* __restrict__ bc, const float2* __restrict__ dc,
    const float* __restrict__ AwsT, float* __restrict__ out)
{
    const int t = threadIdx.x;
    const int blk = blockIdx.x;

    if (blk < K2_M2) {
        int e = blk * 256 + t;
        int p, d; bool live;
        decode_item<2>(e, p, d, live);
        chain_LT<4>(p, d, live, bc, dc, AwsT, out);
    } else if (blk < K2_M2 + K2_M3) {
        int e = (blk - K2_M2) * 256 + t;
        int p, d; bool live;
        decode_item<3>(e, p, d, live);
        chain_RT(p, d, 8, live, bc, dc, AwsT, out);
    } else if (blk < K2_M2 + K2_M3 + K2_M4) {
        int e = (blk - K2_M2 - K2_M3) * 256 + t;
        int p, d; bool live;
        decode_item<4>(e, p, d, live);
        chain_RT(p, d, 16, live, bc, dc, AwsT, out);
    } else {
        const int wv = t >> 6;
        const int lane = t & 63;
        int waveid = (blk - (K2_M2 + K2_M3 + K2_M4)) * 4 + wv;  // 0..3071
        int pix = waveid / DIN;
        int d = waveid - pix * DIN;
        int batch = pix >> 4;
        int sel = pix & 15;
        int r = ((sel >> 2) + 1) * 32 - 1;
        int c = ((sel & 3) + 1) * 32 - 1;
        int p = batch * HW + r * WW + c;
        int m = __builtin_ctz(r + 1);
        int mc = __builtin_ctz(c + 1);
        if (mc < m) m = mc;
        int L = 1 << m;

        float An[16];
        load_An(AwsT, d, An);
        float acc16[16];
        #pragma unroll
        for (int n = 0; n < 16; ++n) acc16[n] = 0.0f;
        float Scarry = 0.0f;

        for (int jb = 0; jb < L; jb += 64) {
            int j = jb + lane;
            bool act = (j < L);
            int jc = act ? j : 0;
            int pj = p - DIAG * jc;
            float2 v = dc[(size_t)pj * 96 + d];
            float dj = act ? v.x : 0.0f;
            float cj = (j >= 1 && act) ? v.y : 0.0f;

            float incl = dj;
            #pragma unroll
            for (int off = 1; off < 64; off <<= 1) {
                float u = __shfl_up(incl, off);
                if (lane >= off) incl += u;
            }
            float S = Scarry + incl - dj;

            const float* rb = bc + (size_t)pj * 32;
            float4 B0 = *reinterpret_cast<const float4*>(rb);
            float4 B1 = *reinterpret_cast<const float4*>(rb + 4);
            float4 B2 = *reinterpret_cast<const float4*>(rb + 8);
            float4 B3 = *reinterpret_cast<const float4*>(rb + 12);
            float Bv[16] = {B0.x,B0.y,B0.z,B0.w, B1.x,B1.y,B1.z,B1.w,
                            B2.x,B2.y,B2.z,B2.w, B3.x,B3.y,B3.z,B3.w};
            #pragma unroll
            for (int n = 0; n < 16; ++n)
                acc16[n] = fmaf(exp2f(An[n] * S) * Bv[n], cj, acc16[n]);

            Scarry += __shfl(incl, 63);
        }

        #pragma unroll
        for (int off = 32; off >= 1; off >>= 1) {
            #pragma unroll
            for (int n = 0; n < 16; ++n) acc16[n] += __shfl_xor(acc16[n], off);
        }

        if (lane == 0) {
            float y = c_dot(bc + (size_t)p * 32 + 16, acc16);
            out[(size_t)p * 96 + d] += y;
        }
    }
}

extern "C" void kernel_launch(void* const* d_in, const int* in_sizes, int n_in,
                              void* d_out, int out_size, void* d_ws, size_t ws_size,
                              hipStream_t stream) {
    const float* x    = (const float*)d_in[0];
    const float* W1   = (const float*)d_in[1];
    const float* b1   = (const float*)d_in[2];
    const float* dtw  = (const float*)d_in[3];
    const float* dtb  = (const float*)d_in[4];
    const float* alog = (const float*)d_in[5];
    const float* Dv   = (const float*)d_in[6];
    float* out = (float*)d_out;

    char* ws = (char*)d_ws;
    float2* dc  = (float2*)(ws);                 // NPIX*96*8 (quarter-touched)
    float*  bcb = (float*)(ws + 25165824);       // NPIX*32*4 (quarter-touched)
    float*  Aws = (float*)(ws + 29360128);       // 1536*4

    hipLaunchKernelGGL(ssm2d_dbc, dim3(512), dim3(512), 0, stream,
                       x, W1, b1, dtw, dtb, alog, Dv,
                       bcb, dc, Aws, out);
    hipLaunchKernelGGL(ssm2d_scan, dim3(K2_M2 + K2_M3 + K2_M4 + K2_LONG), dim3(256), 0, stream,
                       bcb, dc, Aws, out);
}

// Round 19
// 39.785 us; speedup vs baseline: 2.9692x; 1.0380x over previous
//
#include <hip/hip_runtime.h>
#include <cstdint>

#define CIN 96
#define DIN 96
#define DTR 8
#define DST 16
#define HH 128
#define WW 128
#define HW (HH*WW)
#define NPIX (2*HW)       // B=2
#define DIAG (WW+1)       // global diagonal step = 129
#define LOG2E 1.4426950408889634f

__device__ __forceinline__ float softplus_f(float t) {
    return (t > 20.0f) ? t : __logf(1.0f + __expf(t));
}

__device__ __forceinline__ void load_An(const float* __restrict__ AwsT, int d, float* An) {
    float4 A0 = *reinterpret_cast<const float4*>(AwsT + d * 16);
    float4 A1 = *reinterpret_cast<const float4*>(AwsT + d * 16 + 4);
    float4 A2 = *reinterpret_cast<const float4*>(AwsT + d * 16 + 8);
    float4 A3 = *reinterpret_cast<const float4*>(AwsT + d * 16 + 12);
    An[0]=A0.x; An[1]=A0.y; An[2]=A0.z; An[3]=A0.w;
    An[4]=A1.x; An[5]=A1.y; An[6]=A1.z; An[7]=A1.w;
    An[8]=A2.x; An[9]=A2.y; An[10]=A2.z; An[11]=A2.w;
    An[12]=A3.x; An[13]=A3.y; An[14]=A3.z; An[15]=A3.w;
}

__device__ __forceinline__ float c_dot(const float* __restrict__ rc, const float* acc16) {
    float4 C0 = *reinterpret_cast<const float4*>(rc);
    float4 C1 = *reinterpret_cast<const float4*>(rc + 4);
    float4 C2 = *reinterpret_cast<const float4*>(rc + 8);
    float4 C3 = *reinterpret_cast<const float4*>(rc + 12);
    float ys = 0.f;
    ys = fmaf(acc16[0],C0.x,ys); ys = fmaf(acc16[1],C0.y,ys);
    ys = fmaf(acc16[2],C0.z,ys); ys = fmaf(acc16[3],C0.w,ys);
    ys = fmaf(acc16[4],C1.x,ys); ys = fmaf(acc16[5],C1.y,ys);
    ys = fmaf(acc16[6],C1.z,ys); ys = fmaf(acc16[7],C1.w,ys);
    ys = fmaf(acc16[8],C2.x,ys); ys = fmaf(acc16[9],C2.y,ys);
    ys = fmaf(acc16[10],C2.z,ys); ys = fmaf(acc16[11],C2.w,ys);
    ys = fmaf(acc16[12],C3.x,ys); ys = fmaf(acc16[13],C3.y,ys);
    ys = fmaf(acc16[14],C3.z,ys); ys = fmaf(acc16[15],C3.w,ys);
    return ys;
}

// ---------------- Kernel 1: 2x32 tile: GEMV + delta + base out + in-LDS L=2 chains ----------------
__global__ __launch_bounds__(512) void ssm2d_dbc(
    const float* __restrict__ x,
    const float* __restrict__ W1, const float* __restrict__ b1,
    const float* __restrict__ dtw, const float* __restrict__ dtb,
    const float* __restrict__ alog, const float* __restrict__ Dv,
    float* __restrict__ bc, float2* __restrict__ dc,
    float* __restrict__ Aws, float* __restrict__ out)
{
    __shared__ float sX[CIN][65];      // x[ch][px]
    __shared__ float sOut[64][41];     // 40 matvec outputs per pixel
    __shared__ float sDelta[DIN][65];  // delta[d][px]
    __shared__ float sAn[DIN][17];     // -exp(A_log)*log2e, padded
    __shared__ float sBC[64];          // dot(B,C) per pixel

    const int t = threadIdx.x;
    const int blk = blockIdx.x;          // 0..511
    const int b = blk >> 8;
    const int tile = blk & 255;
    const int a = tile >> 2;             // row-pair 0..63
    const int b2 = tile & 3;             // col-tile 0..3
    const int r0 = a << 1;
    const int c0 = b2 << 5;
    const float* xb = x + (size_t)b * CIN * HW;

    // load x tile (96 ch x 64 px) as float4
    #pragma unroll
    for (int it = 0; it < 3; ++it) {
        int i4 = it * 512 + t;           // < 1536
        int ch = i4 >> 4;
        int px4 = (i4 & 15) << 2;
        int row = r0 + (px4 >> 5);
        int col = c0 + (px4 & 31);
        float4 v = *reinterpret_cast<const float4*>(xb + (size_t)ch * HW + row * WW + col);
        sX[ch][px4 + 0] = v.x; sX[ch][px4 + 1] = v.y;
        sX[ch][px4 + 2] = v.z; sX[ch][px4 + 3] = v.w;
    }
    // A table (LDS; block 0 publishes global copy for kernel 2)
    for (int i = t; i < DIN * DST; i += 512) {
        float v = -__expf(alog[i]) * LOG2E;
        sAn[i >> 4][i & 15] = v;
        if (blk == 0) Aws[i] = v;
    }
    __syncthreads();

    // GEMV: wave w computes outputs [5w,5w+5), lane = pixel
    const int lane = t & 63;
    const int w = __builtin_amdgcn_readfirstlane(t >> 6);   // 0..7
    const int og = w * 5;
    float a0 = b1[og + 0], a1 = b1[og + 1], a2 = b1[og + 2],
          a3 = b1[og + 3], a4 = b1[og + 4];
    #pragma unroll 16
    for (int ch = 0; ch < CIN; ++ch) {
        float xv = sX[ch][lane];
        a0 = fmaf(xv, W1[(og + 0) * CIN + ch], a0);
        a1 = fmaf(xv, W1[(og + 1) * CIN + ch], a1);
        a2 = fmaf(xv, W1[(og + 2) * CIN + ch], a2);
        a3 = fmaf(xv, W1[(og + 3) * CIN + ch], a3);
        a4 = fmaf(xv, W1[(og + 4) * CIN + ch], a4);
    }
    sOut[lane][og + 0] = a0; sOut[lane][og + 1] = a1; sOut[lane][og + 2] = a2;
    sOut[lane][og + 3] = a3; sOut[lane][og + 4] = a4;
    __syncthreads();

    if (t < 64) {
        float s = 0.f;
        #pragma unroll
        for (int n = 0; n < DST; ++n) s += sOut[t][8 + n] * sOut[t][24 + n];
        sBC[t] = s;
    }
    __syncthreads();

    // epilogue: delta + base out + sDelta; sparse dc ((r-c) % 4 == 0)
    #pragma unroll
    for (int it = 0; it < 12; ++it) {
        int i = it * 512 + t;            // < 6144
        int px = i / 96;
        int d = i - px * 96;
        float tt = dtb[d];
        float4 wA = *reinterpret_cast<const float4*>(dtw + d * DTR);
        float4 wB = *reinterpret_cast<const float4*>(dtw + d * DTR + 4);
        tt = fmaf(sOut[px][0], wA.x, tt); tt = fmaf(sOut[px][1], wA.y, tt);
        tt = fmaf(sOut[px][2], wA.z, tt); tt = fmaf(sOut[px][3], wA.w, tt);
        tt = fmaf(sOut[px][4], wB.x, tt); tt = fmaf(sOut[px][5], wB.y, tt);
        tt = fmaf(sOut[px][6], wB.z, tt); tt = fmaf(sOut[px][7], wB.w, tt);
        float delta = softplus_f(tt);
        float xv = sX[d][px];
        sDelta[d][px] = delta;
        int rg = r0 + (px >> 5), cg = c0 + (px & 31);
        size_t pg = (size_t)b * HW + rg * WW + cg;
        out[pg * 96 + d] = xv * fmaf(delta, sBC[px], Dv[d]);
        if (((rg - cg) & 3) == 0)
            dc[pg * 96 + d] = make_float2(delta, delta * xv);
    }
    // sparse bc writeout ((r-c) % 4 == 0 pixels)
    #pragma unroll
    for (int it = 0; it < 4; ++it) {
        int i = it * 512 + t;            // < 2048
        int px = i >> 5;
        int n = i & 31;
        int rg = r0 + (px >> 5), cg = c0 + (px & 31);
        if (((rg - cg) & 3) == 0) {
            size_t pg = (size_t)b * HW + rg * WW + cg;
            bc[pg * 32 + n] = sOut[px][8 + n];
        }
    }
    __syncthreads();   // sDelta ready

    // in-LDS M1 chains (L=2): dst = (2a+1, c0+1+2k), anc = (2a, c0+2k); exact m==1 only
    for (int ii = t; ii < 16 * 96; ii += 512) {
        int k = ii / 96;                 // 0..15
        int d = ii - k * 96;
        bool live = !((a & 1) && (k & 1));   // m==1 iff !(r%4==3 && c%4==3)
        int pxd = 33 + 2 * k;
        int anc = 2 * k;
        float ddst = sDelta[d][pxd];
        float ca = sDelta[d][anc] * sX[d][anc];
        float y = 0.f;
        #pragma unroll
        for (int n = 0; n < 16; ++n)
            y = fmaf(sOut[pxd][24 + n] * exp2f(sAn[d][n] * ddst) * sOut[anc][8 + n], ca, y);
        if (live) {
            int rg = r0 + 1, cg = c0 + 1 + 2 * k;
            size_t g = ((size_t)b * HW + rg * WW + cg) * 96 + d;
            out[g] += y;
        }
    }
}

// decode item for section M (exact-m check) -> (p, d, live)
template<int M>
__device__ __forceinline__ void decode_item(int e, int& p, int& d, bool& live) {
    d = e % 96;
    int pxi = e / 96;
    const int sh = 7 - M;
    const int nM = 1 << sh;
    const int half = nM * nM;
    int img = pxi >= half;
    int e2 = pxi - (img ? half : 0);
    int rr = e2 >> sh;
    int cc = e2 & (nM - 1);
    live = ((rr & cc & 1) == 0);
    int r = ((rr + 1) << M) - 1;
    int c = ((cc + 1) << M) - 1;
    p = img * HW + r * WW + c;
}

template<int L>
__device__ __forceinline__ void chain_LT(int p, int d, bool live,
    const float* __restrict__ bc, const float2* __restrict__ dc,
    const float* __restrict__ AwsT, float* __restrict__ out)
{
    size_t base = (size_t)p * 96 + d;
    float2 v0 = dc[base];
    float2 vj[L - 1];
    #pragma unroll
    for (int j = 1; j < L; ++j)
        vj[j - 1] = dc[(size_t)(p - j * DIAG) * 96 + d];
    float An[16];
    load_An(AwsT, d, An);
    float acc16[16];
    #pragma unroll
    for (int n = 0; n < 16; ++n) acc16[n] = 0.f;
    float S = v0.x;
    #pragma unroll
    for (int j = 1; j < L; ++j) {
        const float* rb = bc + (size_t)(p - j * DIAG) * 32;
        float4 B0 = *reinterpret_cast<const float4*>(rb);
        float4 B1 = *reinterpret_cast<const float4*>(rb + 4);
        float4 B2 = *reinterpret_cast<const float4*>(rb + 8);
        float4 B3 = *reinterpret_cast<const float4*>(rb + 12);
        float Bv[16] = {B0.x,B0.y,B0.z,B0.w, B1.x,B1.y,B1.z,B1.w,
                        B2.x,B2.y,B2.z,B2.w, B3.x,B3.y,B3.z,B3.w};
        float cj = vj[j - 1].y;
        #pragma unroll
        for (int n = 0; n < 16; ++n)
            acc16[n] = fmaf(exp2f(An[n] * S) * Bv[n], cj, acc16[n]);
        S += vj[j - 1].x;
    }
    float ys = c_dot(bc + (size_t)p * 32 + 16, acc16);
    if (live) out[base] += ys;
}

__device__ __forceinline__ void chain_RT(int p, int d, int L, bool live,
    const float* __restrict__ bc, const float2* __restrict__ dc,
    const float* __restrict__ AwsT, float* __restrict__ out)
{
    size_t base = (size_t)p * 96 + d;
    float An[16];
    load_An(AwsT, d, An);
    float acc16[16];
    #pragma unroll
    for (int n = 0; n < 16; ++n) acc16[n] = 0.f;
    float S = dc[base].x;
    int pj = p;
    for (int j = 1; j < L; ++j) {
        pj -= DIAG;
        float2 v = dc[(size_t)pj * 96 + d];
        const float* rb = bc + (size_t)pj * 32;
        float4 B0 = *reinterpret_cast<const float4*>(rb);
        float4 B1 = *reinterpret_cast<const float4*>(rb + 4);
        float4 B2 = *reinterpret_cast<const float4*>(rb + 8);
        float4 B3 = *reinterpret_cast<const float4*>(rb + 12);
        float Bv[16] = {B0.x,B0.y,B0.z,B0.w, B1.x,B1.y,B1.z,B1.w,
                        B2.x,B2.y,B2.z,B2.w, B3.x,B3.y,B3.z,B3.w};
        #pragma unroll
        for (int n = 0; n < 16; ++n)
            acc16[n] = fmaf(exp2f(An[n] * S) * Bv[n], v.y, acc16[n]);
        S += v.x;
    }
    float ys = c_dot(bc + (size_t)p * 32 + 16, acc16);
    if (live) out[base] += ys;
}

// ---------------- Kernel 2: M2 (L=4), M3 (L=8), M4 (L=16), long (m>=5) ----------------
#define K2_M2 768
#define K2_M3 192
#define K2_M4 48
#define K2_LONG 768
__global__ __launch_bounds__(256) void ssm2d_scan(
    const float* __restrict__ bc, const float2* __restrict__ dc,
    const float* __restrict__ AwsT, float* __restrict__ out)
{
    const int t = threadIdx.x;
    const int blk = blockIdx.x;

    if (blk < K2_M2) {
        int e = blk * 256 + t;
        int p, d; bool live;
        decode_item<2>(e, p, d, live);
        chain_LT<4>(p, d, live, bc, dc, AwsT, out);
    } else if (blk < K2_M2 + K2_M3) {
        int e = (blk - K2_M2) * 256 + t;
        int p, d; bool live;
        decode_item<3>(e, p, d, live);
        chain_RT(p, d, 8, live, bc, dc, AwsT, out);
    } else if (blk < K2_M2 + K2_M3 + K2_M4) {
        int e = (blk - K2_M2 - K2_M3) * 256 + t;
        int p, d; bool live;
        decode_item<4>(e, p, d, live);
        chain_RT(p, d, 16, live, bc, dc, AwsT, out);
    } else {
        const int wv = t >> 6;
        const int lane = t & 63;
        int waveid = (blk - (K2_M2 + K2_M3 + K2_M4)) * 4 + wv;  // 0..3071
        int pix = waveid / DIN;
        int d = waveid - pix * DIN;
        int batch = pix >> 4;
        int sel = pix & 15;
        int r = ((sel >> 2) + 1) * 32 - 1;
        int c = ((sel & 3) + 1) * 32 - 1;
        int p = batch * HW + r * WW + c;
        int m = __builtin_ctz(r + 1);
        int mc = __builtin_ctz(c + 1);
        if (mc < m) m = mc;
        int L = 1 << m;

        float An[16];
        load_An(AwsT, d, An);
        float acc16[16];
        #pragma unroll
        for (int n = 0; n < 16; ++n) acc16[n] = 0.0f;
        float Scarry = 0.0f;

        for (int jb = 0; jb < L; jb += 64) {
            int j = jb + lane;
            bool act = (j < L);
            int jc = act ? j : 0;
            int pj = p - DIAG * jc;
            float2 v = dc[(size_t)pj * 96 + d];
            float dj = act ? v.x : 0.0f;
            float cj = (j >= 1 && act) ? v.y : 0.0f;

            float incl = dj;
            #pragma unroll
            for (int off = 1; off < 64; off <<= 1) {
                float u = __shfl_up(incl, off);
                if (lane >= off) incl += u;
            }
            float S = Scarry + incl - dj;

            const float* rb = bc + (size_t)pj * 32;
            float4 B0 = *reinterpret_cast<const float4*>(rb);
            float4 B1 = *reinterpret_cast<const float4*>(rb + 4);
            float4 B2 = *reinterpret_cast<const float4*>(rb + 8);
            float4 B3 = *reinterpret_cast<const float4*>(rb + 12);
            float Bv[16] = {B0.x,B0.y,B0.z,B0.w, B1.x,B1.y,B1.z,B1.w,
                            B2.x,B2.y,B2.z,B2.w, B3.x,B3.y,B3.z,B3.w};
            #pragma unroll
            for (int n = 0; n < 16; ++n)
                acc16[n] = fmaf(exp2f(An[n] * S) * Bv[n], cj, acc16[n]);

            Scarry += __shfl(incl, 63);
        }

        #pragma unroll
        for (int off = 32; off >= 1; off >>= 1) {
            #pragma unroll
            for (int n = 0; n < 16; ++n) acc16[n] += __shfl_xor(acc16[n], off);
        }

        if (lane == 0) {
            float y = c_dot(bc + (size_t)p * 32 + 16, acc16);
            out[(size_t)p * 96 + d] += y;
        }
    }
}

extern "C" void kernel_launch(void* const* d_in, const int* in_sizes, int n_in,
                              void* d_out, int out_size, void* d_ws, size_t ws_size,
                              hipStream_t stream) {
    const float* x    = (const float*)d_in[0];
    const float* W1   = (const float*)d_in[1];
    const float* b1   = (const float*)d_in[2];
    const float* dtw  = (const float*)d_in[3];
    const float* dtb  = (const float*)d_in[4];
    const float* alog = (const float*)d_in[5];
    const float* Dv   = (const float*)d_in[6];
    float* out = (float*)d_out;

    char* ws = (char*)d_ws;
    float2* dc  = (float2*)(ws);                 // NPIX*96*8 (quarter-touched)
    float*  bcb = (float*)(ws + 25165824);       // NPIX*32*4 (quarter-touched)
    float*  Aws = (float*)(ws + 29360128);       // 1536*4

    hipLaunchKernelGGL(ssm2d_dbc, dim3(512), dim3(512), 0, stream,
                       x, W1, b1, dtw, dtb, alog, Dv,
                       bcb, dc, Aws, out);
    hipLaunchKernelGGL(ssm2d_scan, dim3(K2_M2 + K2_M3 + K2_M4 + K2_LONG), dim3(256), 0, stream,
                       bcb, dc, Aws, out);
}

// Round 20
// 36.752 us; speedup vs baseline: 3.2143x; 1.0825x over previous
//
#include <hip/hip_runtime.h>
#include <cstdint>

#define CIN 96
#define DIN 96
#define DTR 8
#define DST 16
#define HH 128
#define WW 128
#define HW (HH*WW)
#define NPIX (2*HW)       // B=2
#define LOG2E 1.4426950408889634f
#define NDIAG 63          // diagonals with (r-c) % 4 == 0
#define DSLOT 128         // padded slots per diagonal

__device__ __forceinline__ float softplus_f(float t) {
    return (t > 20.0f) ? t : __logf(1.0f + __expf(t));
}

__device__ __forceinline__ void load_An(const float* __restrict__ AwsT, int d, float* An) {
    float4 A0 = *reinterpret_cast<const float4*>(AwsT + d * 16);
    float4 A1 = *reinterpret_cast<const float4*>(AwsT + d * 16 + 4);
    float4 A2 = *reinterpret_cast<const float4*>(AwsT + d * 16 + 8);
    float4 A3 = *reinterpret_cast<const float4*>(AwsT + d * 16 + 12);
    An[0]=A0.x; An[1]=A0.y; An[2]=A0.z; An[3]=A0.w;
    An[4]=A1.x; An[5]=A1.y; An[6]=A1.z; An[7]=A1.w;
    An[8]=A2.x; An[9]=A2.y; An[10]=A2.z; An[11]=A2.w;
    An[12]=A3.x; An[13]=A3.y; An[14]=A3.z; An[15]=A3.w;
}

__device__ __forceinline__ float c_dot(const float* __restrict__ rc, const float* acc16) {
    float4 C0 = *reinterpret_cast<const float4*>(rc);
    float4 C1 = *reinterpret_cast<const float4*>(rc + 4);
    float4 C2 = *reinterpret_cast<const float4*>(rc + 8);
    float4 C3 = *reinterpret_cast<const float4*>(rc + 12);
    float ys = 0.f;
    ys = fmaf(acc16[0],C0.x,ys); ys = fmaf(acc16[1],C0.y,ys);
    ys = fmaf(acc16[2],C0.z,ys); ys = fmaf(acc16[3],C0.w,ys);
    ys = fmaf(acc16[4],C1.x,ys); ys = fmaf(acc16[5],C1.y,ys);
    ys = fmaf(acc16[6],C1.z,ys); ys = fmaf(acc16[7],C1.w,ys);
    ys = fmaf(acc16[8],C2.x,ys); ys = fmaf(acc16[9],C2.y,ys);
    ys = fmaf(acc16[10],C2.z,ys); ys = fmaf(acc16[11],C2.w,ys);
    ys = fmaf(acc16[12],C3.x,ys); ys = fmaf(acc16[13],C3.y,ys);
    ys = fmaf(acc16[14],C3.z,ys); ys = fmaf(acc16[15],C3.w,ys);
    return ys;
}

// ---------------- Kernel 1: 2x32 tile: GEMV + delta + base out + in-LDS L=2 chains ----------------
__global__ __launch_bounds__(512) void ssm2d_dbc(
    const float* __restrict__ x,
    const float* __restrict__ W1, const float* __restrict__ b1,
    const float* __restrict__ dtw, const float* __restrict__ dtb,
    const float* __restrict__ alog, const float* __restrict__ Dv,
    float* __restrict__ bc, float2* __restrict__ dc,
    float* __restrict__ Aws, float* __restrict__ out)
{
    __shared__ float sX[CIN][65];      // x[ch][px]
    __shared__ float sOut[64][41];     // 40 matvec outputs per pixel
    __shared__ float sDelta[DIN][65];  // delta[d][px]
    __shared__ float sAn[DIN][17];     // -exp(A_log)*log2e, padded
    __shared__ float sBC[64];          // dot(B,C) per pixel

    const int t = threadIdx.x;
    const int blk = blockIdx.x;          // 0..511
    const int b = blk >> 8;
    const int tile = blk & 255;
    const int a = tile >> 2;             // row-pair 0..63
    const int b2 = tile & 3;             // col-tile 0..3
    const int r0 = a << 1;
    const int c0 = b2 << 5;
    const float* xb = x + (size_t)b * CIN * HW;

    // load x tile (96 ch x 64 px) as float4
    #pragma unroll
    for (int it = 0; it < 3; ++it) {
        int i4 = it * 512 + t;           // < 1536
        int ch = i4 >> 4;
        int px4 = (i4 & 15) << 2;
        int row = r0 + (px4 >> 5);
        int col = c0 + (px4 & 31);
        float4 v = *reinterpret_cast<const float4*>(xb + (size_t)ch * HW + row * WW + col);
        sX[ch][px4 + 0] = v.x; sX[ch][px4 + 1] = v.y;
        sX[ch][px4 + 2] = v.z; sX[ch][px4 + 3] = v.w;
    }
    // A table (LDS; block 0 publishes global copy for kernel 2)
    for (int i = t; i < DIN * DST; i += 512) {
        float v = -__expf(alog[i]) * LOG2E;
        sAn[i >> 4][i & 15] = v;
        if (blk == 0) Aws[i] = v;
    }
    __syncthreads();

    // GEMV: wave w computes outputs [5w,5w+5), lane = pixel
    const int lane = t & 63;
    const int w = __builtin_amdgcn_readfirstlane(t >> 6);   // 0..7
    const int og = w * 5;
    float a0 = b1[og + 0], a1 = b1[og + 1], a2 = b1[og + 2],
          a3 = b1[og + 3], a4 = b1[og + 4];
    #pragma unroll 16
    for (int ch = 0; ch < CIN; ++ch) {
        float xv = sX[ch][lane];
        a0 = fmaf(xv, W1[(og + 0) * CIN + ch], a0);
        a1 = fmaf(xv, W1[(og + 1) * CIN + ch], a1);
        a2 = fmaf(xv, W1[(og + 2) * CIN + ch], a2);
        a3 = fmaf(xv, W1[(og + 3) * CIN + ch], a3);
        a4 = fmaf(xv, W1[(og + 4) * CIN + ch], a4);
    }
    sOut[lane][og + 0] = a0; sOut[lane][og + 1] = a1; sOut[lane][og + 2] = a2;
    sOut[lane][og + 3] = a3; sOut[lane][og + 4] = a4;
    __syncthreads();

    if (t < 64) {
        float s = 0.f;
        #pragma unroll
        for (int n = 0; n < DST; ++n) s += sOut[t][8 + n] * sOut[t][24 + n];
        sBC[t] = s;
    }
    __syncthreads();

    // epilogue: delta + base out + sDelta; diagonal-compacted dc ((r-c) % 4 == 0)
    #pragma unroll
    for (int it = 0; it < 12; ++it) {
        int i = it * 512 + t;            // < 6144
        int px = i / 96;
        int d = i - px * 96;
        float tt = dtb[d];
        float4 wA = *reinterpret_cast<const float4*>(dtw + d * DTR);
        float4 wB = *reinterpret_cast<const float4*>(dtw + d * DTR + 4);
        tt = fmaf(sOut[px][0], wA.x, tt); tt = fmaf(sOut[px][1], wA.y, tt);
        tt = fmaf(sOut[px][2], wA.z, tt); tt = fmaf(sOut[px][3], wA.w, tt);
        tt = fmaf(sOut[px][4], wB.x, tt); tt = fmaf(sOut[px][5], wB.y, tt);
        tt = fmaf(sOut[px][6], wB.z, tt); tt = fmaf(sOut[px][7], wB.w, tt);
        float delta = softplus_f(tt);
        float xv = sX[d][px];
        sDelta[d][px] = delta;
        int rg = r0 + (px >> 5), cg = c0 + (px & 31);
        size_t pg = (size_t)b * HW + rg * WW + cg;
        out[pg * 96 + d] = xv * fmaf(delta, sBC[px], Dv[d]);
        if (((rg - cg) & 3) == 0) {
            int td = ((rg - cg) >> 2) + 31;
            int jd = (rg < cg) ? rg : cg;
            size_t row = (size_t)(b * NDIAG + td) * DSLOT + jd;
            dc[row * 96 + d] = make_float2(delta, delta * xv);
        }
    }
    // diagonal-compacted bc writeout ((r-c) % 4 == 0 pixels)
    #pragma unroll
    for (int it = 0; it < 4; ++it) {
        int i = it * 512 + t;            // < 2048
        int px = i >> 5;
        int n = i & 31;
        int rg = r0 + (px >> 5), cg = c0 + (px & 31);
        if (((rg - cg) & 3) == 0) {
            int td = ((rg - cg) >> 2) + 31;
            int jd = (rg < cg) ? rg : cg;
            size_t row = (size_t)(b * NDIAG + td) * DSLOT + jd;
            bc[row * 32 + n] = sOut[px][8 + n];
        }
    }
    __syncthreads();   // sDelta ready

    // in-LDS M1 chains (L=2): dst = (2a+1, c0+1+2k), anc = (2a, c0+2k); exact m==1 only
    for (int ii = t; ii < 16 * 96; ii += 512) {
        int k = ii / 96;                 // 0..15
        int d = ii - k * 96;
        bool live = !((a & 1) && (k & 1));   // m==1 iff !(r%4==3 && c%4==3)
        int pxd = 33 + 2 * k;
        int anc = 2 * k;
        float ddst = sDelta[d][pxd];
        float ca = sDelta[d][anc] * sX[d][anc];
        float y = 0.f;
        #pragma unroll
        for (int n = 0; n < 16; ++n)
            y = fmaf(sOut[pxd][24 + n] * exp2f(sAn[d][n] * ddst) * sOut[anc][8 + n], ca, y);
        if (live) {
            int rg = r0 + 1, cg = c0 + 1 + 2 * k;
            size_t g = ((size_t)b * HW + rg * WW + cg) * 96 + d;
            out[g] += y;
        }
    }
}

// decode item for section M (exact-m check) -> (out index, diagonal row, d, live)
template<int M>
__device__ __forceinline__ void decode_item(int e, size_t& obase, size_t& drow,
                                            int& d, bool& live) {
    d = e % 96;
    int pxi = e / 96;
    const int sh = 7 - M;
    const int nM = 1 << sh;
    const int half = nM * nM;
    int img = pxi >= half;
    int e2 = pxi - (img ? half : 0);
    int rr = e2 >> sh;
    int cc = e2 & (nM - 1);
    live = ((rr & cc & 1) == 0);
    int r = ((rr + 1) << M) - 1;
    int c = ((cc + 1) << M) - 1;
    obase = ((size_t)(img * HW + r * WW + c)) * 96 + d;
    int td = ((r - c) >> 2) + 31;
    int jd = (r < c) ? r : c;
    drow = (size_t)(img * NDIAG + td) * DSLOT + jd;
}

template<int L>
__device__ __forceinline__ void chain_LT(size_t obase, size_t drow, int d, bool live,
    const float* __restrict__ bc, const float2* __restrict__ dc,
    const float* __restrict__ AwsT, float* __restrict__ out)
{
    float2 v0 = dc[drow * 96 + d];
    float2 vj[L - 1];
    #pragma unroll
    for (int j = 1; j < L; ++j)
        vj[j - 1] = dc[(drow - j) * 96 + d];
    float An[16];
    load_An(AwsT, d, An);
    float acc16[16];
    #pragma unroll
    for (int n = 0; n < 16; ++n) acc16[n] = 0.f;
    float S = v0.x;
    #pragma unroll
    for (int j = 1; j < L; ++j) {
        const float* rb = bc + (drow - j) * 32;
        float4 B0 = *reinterpret_cast<const float4*>(rb);
        float4 B1 = *reinterpret_cast<const float4*>(rb + 4);
        float4 B2 = *reinterpret_cast<const float4*>(rb + 8);
        float4 B3 = *reinterpret_cast<const float4*>(rb + 12);
        float Bv[16] = {B0.x,B0.y,B0.z,B0.w, B1.x,B1.y,B1.z,B1.w,
                        B2.x,B2.y,B2.z,B2.w, B3.x,B3.y,B3.z,B3.w};
        float cj = vj[j - 1].y;
        #pragma unroll
        for (int n = 0; n < 16; ++n)
            acc16[n] = fmaf(exp2f(An[n] * S) * Bv[n], cj, acc16[n]);
        S += vj[j - 1].x;
    }
    float ys = c_dot(bc + drow * 32 + 16, acc16);
    if (live) out[obase] += ys;
}

__device__ __forceinline__ void chain_RT(size_t obase, size_t drow, int d, int L, bool live,
    const float* __restrict__ bc, const float2* __restrict__ dc,
    const float* __restrict__ AwsT, float* __restrict__ out)
{
    float An[16];
    load_An(AwsT, d, An);
    float acc16[16];
    #pragma unroll
    for (int n = 0; n < 16; ++n) acc16[n] = 0.f;
    float S = dc[drow * 96 + d].x;
    for (int j = 1; j < L; ++j) {
        float2 v = dc[(drow - j) * 96 + d];
        const float* rb = bc + (drow - j) * 32;
        float4 B0 = *reinterpret_cast<const float4*>(rb);
        float4 B1 = *reinterpret_cast<const float4*>(rb + 4);
        float4 B2 = *reinterpret_cast<const float4*>(rb + 8);
        float4 B3 = *reinterpret_cast<const float4*>(rb + 12);
        float Bv[16] = {B0.x,B0.y,B0.z,B0.w, B1.x,B1.y,B1.z,B1.w,
                        B2.x,B2.y,B2.z,B2.w, B3.x,B3.y,B3.z,B3.w};
        #pragma unroll
        for (int n = 0; n < 16; ++n)
            acc16[n] = fmaf(exp2f(An[n] * S) * Bv[n], v.y, acc16[n]);
        S += v.x;
    }
    float ys = c_dot(bc + drow * 32 + 16, acc16);
    if (live) out[obase] += ys;
}

// ---------------- Kernel 2: M2 (L=4), M3 (L=8), M4 (L=16), long (m>=5) ----------------
#define K2_M2 768
#define K2_M3 192
#define K2_M4 48
#define K2_LONG 768
__global__ __launch_bounds__(256) void ssm2d_scan(
    const float* __restrict__ bc, const float2* __restrict__ dc,
    const float* __restrict__ AwsT, float* __restrict__ out)
{
    const int t = threadIdx.x;
    const int blk = blockIdx.x;

    if (blk < K2_M2) {
        int e = blk * 256 + t;
        size_t obase, drow; int d; bool live;
        decode_item<2>(e, obase, drow, d, live);
        chain_LT<4>(obase, drow, d, live, bc, dc, AwsT, out);
    } else if (blk < K2_M2 + K2_M3) {
        int e = (blk - K2_M2) * 256 + t;
        size_t obase, drow; int d; bool live;
        decode_item<3>(e, obase, drow, d, live);
        chain_RT(obase, drow, d, 8, live, bc, dc, AwsT, out);
    } else if (blk < K2_M2 + K2_M3 + K2_M4) {
        int e = (blk - K2_M2 - K2_M3) * 256 + t;
        size_t obase, drow; int d; bool live;
        decode_item<4>(e, obase, drow, d, live);
        chain_RT(obase, drow, d, 16, live, bc, dc, AwsT, out);
    } else {
        const int wv = t >> 6;
        const int lane = t & 63;
        int waveid = (blk - (K2_M2 + K2_M3 + K2_M4)) * 4 + wv;  // 0..3071
        int pix = waveid / DIN;
        int d = waveid - pix * DIN;
        int batch = pix >> 4;
        int sel = pix & 15;
        int r = ((sel >> 2) + 1) * 32 - 1;
        int c = ((sel & 3) + 1) * 32 - 1;
        int p = batch * HW + r * WW + c;
        int m = __builtin_ctz(r + 1);
        int mc = __builtin_ctz(c + 1);
        if (mc < m) m = mc;
        int L = 1 << m;

        int td = ((r - c) >> 2) + 31;
        int jd = (r < c) ? r : c;
        size_t drow = (size_t)(batch * NDIAG + td) * DSLOT + jd;

        float An[16];
        load_An(AwsT, d, An);
        float acc16[16];
        #pragma unroll
        for (int n = 0; n < 16; ++n) acc16[n] = 0.0f;
        float Scarry = 0.0f;

        for (int jb = 0; jb < L; jb += 64) {
            int j = jb + lane;
            bool act = (j < L);
            int jc = act ? j : 0;
            size_t prow = drow - jc;
            float2 v = dc[prow * 96 + d];
            float dj = act ? v.x : 0.0f;
            float cj = (j >= 1 && act) ? v.y : 0.0f;   // j=0 base already in out

            float incl = dj;
            #pragma unroll
            for (int off = 1; off < 64; off <<= 1) {
                float u = __shfl_up(incl, off);
                if (lane >= off) incl += u;
            }
            float S = Scarry + incl - dj;

            const float* rb = bc + prow * 32;
            float4 B0 = *reinterpret_cast<const float4*>(rb);
            float4 B1 = *reinterpret_cast<const float4*>(rb + 4);
            float4 B2 = *reinterpret_cast<const float4*>(rb + 8);
            float4 B3 = *reinterpret_cast<const float4*>(rb + 12);
            float Bv[16] = {B0.x,B0.y,B0.z,B0.w, B1.x,B1.y,B1.z,B1.w,
                            B2.x,B2.y,B2.z,B2.w, B3.x,B3.y,B3.z,B3.w};
            #pragma unroll
            for (int n = 0; n < 16; ++n)
                acc16[n] = fmaf(exp2f(An[n] * S) * Bv[n], cj, acc16[n]);

            Scarry += __shfl(incl, 63);
        }

        #pragma unroll
        for (int off = 32; off >= 1; off >>= 1) {
            #pragma unroll
            for (int n = 0; n < 16; ++n) acc16[n] += __shfl_xor(acc16[n], off);
        }

        if (lane == 0) {
            float y = c_dot(bc + drow * 32 + 16, acc16);
            out[(size_t)p * 96 + d] += y;
        }
    }
}

extern "C" void kernel_launch(void* const* d_in, const int* in_sizes, int n_in,
                              void* d_out, int out_size, void* d_ws, size_t ws_size,
                              hipStream_t stream) {
    const float* x    = (const float*)d_in[0];
    const float* W1   = (const float*)d_in[1];
    const float* b1   = (const float*)d_in[2];
    const float* dtw  = (const float*)d_in[3];
    const float* dtb  = (const float*)d_in[4];
    const float* alog = (const float*)d_in[5];
    const float* Dv   = (const float*)d_in[6];
    float* out = (float*)d_out;

    char* ws = (char*)d_ws;
    float2* dc  = (float2*)(ws);                 // 2*63*128*96*8  = 12,386,304 B
    float*  bcb = (float*)(ws + 12582912);       // 2*63*128*32*4 =  2,064,384 B
    float*  Aws = (float*)(ws + 14680064);       // 1536*4

    hipLaunchKernelGGL(ssm2d_dbc, dim3(512), dim3(512), 0, stream,
                       x, W1, b1, dtw, dtb, alog, Dv,
                       bcb, dc, Aws, out);
    hipLaunchKernelGGL(ssm2d_scan, dim3(K2_M2 + K2_M3 + K2_M4 + K2_LONG), dim3(256), 0, stream,
                       bcb, dc, Aws, out);
}